// Round 3
// baseline (170.661 us; speedup 1.0000x reference)
//
#include <hip/hip_runtime.h>

#define B_N  128
#define VIS  4096
#define HID  4096
#define EMB  512
#define NNEG 2048
#define OUTN (NNEG + 1)

using f32x4  = __attribute__((ext_vector_type(4))) float;
using bf16x8 = __attribute__((ext_vector_type(8))) short;

static __device__ __forceinline__ unsigned short f2bf(float f) {
  unsigned u = __builtin_bit_cast(unsigned, f);
  u += 0x7fffu + ((u >> 16) & 1u);   // RNE
  return (unsigned short)(u >> 16);
}

union U16x8 { unsigned short us[8]; uint4 v; };
union U16x4 { unsigned short us[4]; uint2 v; };

// async global->LDS, 16B per lane; LDS dest = wave-uniform base + lane*16
static __device__ __forceinline__ void glds16(const void* g, void* l) {
  __builtin_amdgcn_global_load_lds(
      (const __attribute__((address_space(1))) unsigned*)g,
      (__attribute__((address_space(3))) unsigned*)l, 16, 0, 0);
}

// prep: vfs fp32 [128,4096] -> Abf bf16 bits; also zero emb (for gemm2 atomics)
__global__ __launch_bounds__(256) void prep_kernel(
    const float* __restrict__ src, unsigned short* __restrict__ dst,
    float* __restrict__ emb) {
  const int idx = blockIdx.x * 256 + threadIdx.x;   // 65536 threads, 8 elem each
  float4 a = ((const float4*)src)[idx * 2];
  float4 b = ((const float4*)src)[idx * 2 + 1];
  U16x8 pk;
  pk.us[0] = f2bf(a.x); pk.us[1] = f2bf(a.y); pk.us[2] = f2bf(a.z); pk.us[3] = f2bf(a.w);
  pk.us[4] = f2bf(b.x); pk.us[5] = f2bf(b.y); pk.us[6] = f2bf(b.z); pk.us[7] = f2bf(b.w);
  ((uint4*)dst)[idx] = pk.v;
  if (idx < (B_N * EMB / 4))
    ((float4*)emb)[idx] = make_float4(0.f, 0.f, 0.f, 0.f);
}

// GEMM1: Hp[split][128][4096] fp32 partial of vfs(bf16) @ W_h^T (+b_h in split 0).
// grid (128 n-tiles, 2 k-splits) = 256 blocks (1/CU), 512 thr (8 waves/CU).
// BM=128 BN=32 BK=64, Kchunk=2048, 32 K-steps. No atomics.
__global__ __launch_bounds__(512, 2) void gemm1_kernel(
    const unsigned short* __restrict__ Abf, const float* __restrict__ Wh,
    const float* __restrict__ bh, float* __restrict__ Hp) {
  const int n0    = blockIdx.x * 32;
  const int kbase = blockIdx.y * 2048;

  __shared__ __align__(16) unsigned short As[128 * 64];  // 16 KB, XOR-swizzled
  __shared__ __align__(16) unsigned short Ws[32 * 64];   // 4 KB

  const int t = threadIdx.x, w = t >> 6, lane = t & 63;
  const int m_lane = lane & 15, kq = lane >> 4;
  f32x4 acc[2] = {};   // wave w: rows w*16..w*16+15, cols n0..n0+31 (2 n-frags)

  // W staging: 32 rows x 64 cols fp32 -> bf16; 4 elems/thread (one float4)
  const int wr = t >> 4, wc = (t & 15) * 4, Gw = (t & 15) >> 1, sub = (t & 1) * 4;
  const float* Wg = Wh + (size_t)(n0 + wr) * VIS + kbase + wc;
  float4 wv = ((const float4*)Wg)[0];
  Wg += 64;

  // A glds map: slot SL = i*512 + w*64 + lane -> row m = SL>>3, pos p = SL&7,
  // stored k-group G = p ^ (m&7) (swizzle applied on the global-address side)
  const int rowA = lane >> 3;
  const int gA   = (lane & 7) ^ rowA;

  for (int kt = 0; kt < 32; ++kt) {
    __syncthreads();   // previous iter's LDS reads complete
#pragma unroll
    for (int i = 0; i < 2; ++i) {
      const int m = i * 64 + w * 8 + rowA;
      const unsigned short* src = Abf + (size_t)m * VIS + kbase + kt * 64 + gA * 8;
      glds16(src, &As[(i * 512 + w * 64) * 8]);
    }
    {
      U16x4 pk;
      pk.us[0] = f2bf(wv.x); pk.us[1] = f2bf(wv.y); pk.us[2] = f2bf(wv.z); pk.us[3] = f2bf(wv.w);
      *(uint2*)&Ws[wr * 64 + ((Gw ^ (wr & 7)) * 8) + sub] = pk.v;
    }
    if (kt < 31) {   // prefetch next W tile (one iter of latency hiding)
      wv = ((const float4*)Wg)[0];
      Wg += 64;
    }
    __syncthreads();  // drains glds (A tile ready)

#pragma unroll
    for (int ks = 0; ks < 2; ++ks) {
      const int Gk = ks * 4 + kq;
      const int m0 = w * 16 + m_lane;
      bf16x8 a0 = *(const bf16x8*)&As[m0 * 64 + ((Gk ^ (m0 & 7)) * 8)];
      const int nA = m_lane, nB = m_lane + 16;
      bf16x8 b0 = *(const bf16x8*)&Ws[nA * 64 + ((Gk ^ (nA & 7)) * 8)];
      bf16x8 b1 = *(const bf16x8*)&Ws[nB * 64 + ((Gk ^ (nB & 7)) * 8)];
      acc[0] = __builtin_amdgcn_mfma_f32_16x16x32_bf16(a0, b0, acc[0], 0, 0, 0);
      acc[1] = __builtin_amdgcn_mfma_f32_16x16x32_bf16(a0, b1, acc[1], 0, 0, 0);
    }
  }

  // epilogue: C/D layout col=lane&15, row=(lane>>4)*4+r; plain fp32 stores
  float* Pd = Hp + (size_t)blockIdx.y * (B_N * HID);
  const int rq = (lane >> 4) * 4;
#pragma unroll
  for (int ni = 0; ni < 2; ++ni) {
    const int ng = n0 + ni * 16 + m_lane;
    const float bias = (blockIdx.y == 0) ? bh[ng] : 0.0f;
#pragma unroll
    for (int r = 0; r < 4; ++r) {
      const int mg = w * 16 + rq + r;
      Pd[(size_t)mg * HID + ng] = acc[ni][r] + bias;
    }
  }
}

// cvt2: Hbf = bf16(Hp[0] + Hp[1]); fused split-K reduce + downconvert
__global__ __launch_bounds__(256) void cvt2_kernel(
    const float* __restrict__ Hp, unsigned short* __restrict__ dst) {
  const int idx = blockIdx.x * 256 + threadIdx.x;   // 65536 threads, 8 elem each
  const float* H1 = Hp + (size_t)B_N * HID;
  float4 a0 = ((const float4*)Hp)[idx * 2];
  float4 b0 = ((const float4*)Hp)[idx * 2 + 1];
  float4 a1 = ((const float4*)H1)[idx * 2];
  float4 b1 = ((const float4*)H1)[idx * 2 + 1];
  U16x8 pk;
  pk.us[0] = f2bf(a0.x + a1.x); pk.us[1] = f2bf(a0.y + a1.y);
  pk.us[2] = f2bf(a0.z + a1.z); pk.us[3] = f2bf(a0.w + a1.w);
  pk.us[4] = f2bf(b0.x + b1.x); pk.us[5] = f2bf(b0.y + b1.y);
  pk.us[6] = f2bf(b0.z + b1.z); pk.us[7] = f2bf(b0.w + b1.w);
  ((uint4*)dst)[idx] = pk.v;
}

// GEMM2: emb[128,512] += hidden(bf16) @ W_e^T (+ b_e in split 0), fp32 atomics.
// grid (32 n-tiles, 8 k-splits), 256 thr. BM=128 BN=16 BK=64, 8 K-steps.
__global__ __launch_bounds__(256, 2) void gemm2_kernel(
    const unsigned short* __restrict__ Hbf, const float* __restrict__ We,
    const float* __restrict__ be, float* __restrict__ emb) {
  const int n0    = blockIdx.x * 16;
  const int kbase = blockIdx.y * 512;

  __shared__ __align__(16) unsigned short As[128 * 64];
  __shared__ __align__(16) unsigned short Ws[16 * 64];

  const int t = threadIdx.x, w = t >> 6, lane = t & 63;
  const int m_lane = lane & 15, kq = lane >> 4;
  f32x4 acc[2] = {};

  const int wr = t >> 4, wc = (t & 15) * 4;
  const float* Wg = We + (size_t)(n0 + wr) * HID + kbase + wc;
  float4 wv = ((const float4*)Wg)[0];
  Wg += 64;

  const int rowA = lane >> 3;
  const int gA   = (lane & 7) ^ rowA;

  for (int kt = 0; kt < 8; ++kt) {
    __syncthreads();
#pragma unroll
    for (int i = 0; i < 4; ++i) {
      const int m = i * 32 + w * 8 + rowA;
      const unsigned short* src = Hbf + (size_t)m * HID + kbase + kt * 64 + gA * 8;
      glds16(src, &As[(i * 256 + w * 64) * 8]);
    }
    {
      U16x4 pk;
      pk.us[0] = f2bf(wv.x); pk.us[1] = f2bf(wv.y); pk.us[2] = f2bf(wv.z); pk.us[3] = f2bf(wv.w);
      const int G = (t & 15) >> 1;
      *(uint2*)&Ws[wr * 64 + ((G ^ (wr & 7)) * 8) + (t & 1) * 4] = pk.v;
    }
    if (kt < 7) { wv = ((const float4*)Wg)[0]; Wg += 64; }
    __syncthreads();

#pragma unroll
    for (int ks = 0; ks < 2; ++ks) {
      const int Gk = ks * 4 + kq;
      const int m0 = w * 32 + m_lane, m1 = m0 + 16;
      bf16x8 a0 = *(const bf16x8*)&As[m0 * 64 + ((Gk ^ (m0 & 7)) * 8)];
      bf16x8 a1 = *(const bf16x8*)&As[m1 * 64 + ((Gk ^ (m1 & 7)) * 8)];
      bf16x8 b0 = *(const bf16x8*)&Ws[m_lane * 64 + ((Gk ^ (m_lane & 7)) * 8)];
      acc[0] = __builtin_amdgcn_mfma_f32_16x16x32_bf16(a0, b0, acc[0], 0, 0, 0);
      acc[1] = __builtin_amdgcn_mfma_f32_16x16x32_bf16(a1, b0, acc[1], 0, 0, 0);
    }
  }

  const int rq = (lane >> 4) * 4;
  const int ng = n0 + m_lane;
  const float bias = (blockIdx.y == 0) ? be[ng] : 0.0f;
#pragma unroll
  for (int mi = 0; mi < 2; ++mi) {
#pragma unroll
    for (int r = 0; r < 4; ++r) {
      const int mg = w * 32 + mi * 16 + rq + r;
      atomicAdd(&emb[mg * EMB + ng], acc[mi][r] + bias);
    }
  }
}

// Scores, e-stationary. Blocks 0..1023: 16 b x 16 negatives. 1024..1031: positives.
__global__ __launch_bounds__(256, 2) void score_kernel(
    const float* __restrict__ emb, const float* __restrict__ n_lfs,
    const float* __restrict__ p_lfs, float* __restrict__ out) {
  const int bx = blockIdx.x;
  const int t = threadIdx.x;
  const int s = t & 15, tb = t >> 4;

  if (bx < 1024) {
    const int nc = bx >> 3, bt = bx & 7;
    const int n0 = nc * 16, b0 = bt * 16;
    __shared__ __align__(16) float nl[16 * 576];
#pragma unroll
    for (int i = 0; i < 8; ++i) {
      const int f = t + i * 256;
      const int r = f >> 7, o4 = f & 127;
      float4 v = *(const float4*)(n_lfs + (size_t)(n0 + r) * EMB + o4 * 4);
      *(float4*)&nl[r * 576 + (o4 >> 3) * 36 + (o4 & 7) * 4] = v;
    }
    const float* eb = emb + (size_t)(b0 + tb) * EMB + s * 32;
    float4 ev[8];
#pragma unroll
    for (int i = 0; i < 8; ++i) ev[i] = *(const float4*)(eb + i * 4);
    __syncthreads();

    for (int j = 0; j < 16; ++j) {
      const float* nr = &nl[j * 576 + s * 36];
      float a0 = 0.f, a1 = 0.f, a2 = 0.f, a3 = 0.f;
#pragma unroll
      for (int i = 0; i < 8; ++i) {
        float4 nv = *(const float4*)(nr + i * 4);
        float d0 = fmaxf(nv.x - ev[i].x, 0.f);
        float d1 = fmaxf(nv.y - ev[i].y, 0.f);
        float d2 = fmaxf(nv.z - ev[i].z, 0.f);
        float d3 = fmaxf(nv.w - ev[i].w, 0.f);
        a0 = fmaf(d0, d0, a0); a1 = fmaf(d1, d1, a1);
        a2 = fmaf(d2, d2, a2); a3 = fmaf(d3, d3, a3);
      }
      float ss = (a0 + a1) + (a2 + a3);
      ss += __shfl_xor(ss, 1);
      ss += __shfl_xor(ss, 2);
      ss += __shfl_xor(ss, 4);
      ss += __shfl_xor(ss, 8);
      if (s == 0) out[(size_t)(b0 + tb) * OUTN + 1 + n0 + j] = -sqrtf(ss);
    }
  } else {
    const int b = (bx - 1024) * 16 + tb;
    const float* eb = emb + (size_t)b * EMB + s * 32;
    const float* pb = p_lfs + (size_t)b * EMB + s * 32;
    float a0 = 0.f, a1 = 0.f, a2 = 0.f, a3 = 0.f;
#pragma unroll
    for (int i = 0; i < 8; ++i) {
      float4 pv = *(const float4*)(pb + i * 4);
      float4 ev = *(const float4*)(eb + i * 4);
      float d0 = fmaxf(pv.x - ev.x, 0.f);
      float d1 = fmaxf(pv.y - ev.y, 0.f);
      float d2 = fmaxf(pv.z - ev.z, 0.f);
      float d3 = fmaxf(pv.w - ev.w, 0.f);
      a0 = fmaf(d0, d0, a0); a1 = fmaf(d1, d1, a1);
      a2 = fmaf(d2, d2, a2); a3 = fmaf(d3, d3, a3);
    }
    float ss = (a0 + a1) + (a2 + a3);
    ss += __shfl_xor(ss, 1);
    ss += __shfl_xor(ss, 2);
    ss += __shfl_xor(ss, 4);
    ss += __shfl_xor(ss, 8);
    if (s == 0) out[(size_t)b * OUTN] = -sqrtf(ss);
  }
}

extern "C" void kernel_launch(void* const* d_in, const int* in_sizes, int n_in,
                              void* d_out, int out_size, void* d_ws, size_t ws_size,
                              hipStream_t stream) {
  const float* vfs   = (const float*)d_in[0];
  const float* p_lfs = (const float*)d_in[1];
  const float* n_lfs = (const float*)d_in[2];
  const float* W_h   = (const float*)d_in[3];
  const float* b_h   = (const float*)d_in[4];
  const float* W_e   = (const float*)d_in[5];
  const float* b_e   = (const float*)d_in[6];
  float* out = (float*)d_out;

  // ws layout (6.25 MB): [Hp 2x2MB][emb 256KB][Abf 1MB][Hbf 1MB]
  char* ws = (char*)d_ws;
  float*          Hp  = (float*)ws;
  float*          emb = (float*)(ws + (4u << 20));
  unsigned short* Abf = (unsigned short*)(ws + (4u << 20) + (256u << 10));
  unsigned short* Hbf = (unsigned short*)(ws + (5u << 20) + (256u << 10));

  prep_kernel<<<256, 256, 0, stream>>>(vfs, Abf, emb);
  gemm1_kernel<<<dim3(HID / 32, 2), 512, 0, stream>>>(Abf, W_h, b_h, Hp);
  cvt2_kernel<<<256, 256, 0, stream>>>(Hp, Hbf);
  gemm2_kernel<<<dim3(EMB / 16, 8), 256, 0, stream>>>(Hbf, W_e, b_e, emb);
  score_kernel<<<1032, 256, 0, stream>>>(emb, n_lfs, p_lfs, out);
}

// Round 4
// 160.082 us; speedup vs baseline: 1.0661x; 1.0661x over previous
//
#include <hip/hip_runtime.h>

#define B_N  128
#define VIS  4096
#define HID  4096
#define EMB  512
#define NNEG 2048
#define OUTN (NNEG + 1)

using f32x4  = __attribute__((ext_vector_type(4))) float;
using bf16x8 = __attribute__((ext_vector_type(8))) short;

static __device__ __forceinline__ unsigned short f2bf(float f) {
  unsigned u = __builtin_bit_cast(unsigned, f);
  u += 0x7fffu + ((u >> 16) & 1u);   // RNE
  return (unsigned short)(u >> 16);
}

union U16x8 { unsigned short us[8]; uint4 v; };
union U16x4 { unsigned short us[4]; uint2 v; };
union U16x2 { unsigned short us[2]; unsigned v; };

// LDS-only drain + barrier: global loads stay in flight across it.
// lgkmcnt(0) before s_barrier guarantees this wave's ds_reads are retired
// (data in regs) and ds_writes landed before ANY wave proceeds -> the
// double-buffer read/write turnaround is safe.
#define PIPE_BARRIER() __asm__ volatile("s_waitcnt lgkmcnt(0)\n\ts_barrier" ::: "memory")

// prep: vfs fp32 [128,4096] -> Abf bf16 bits; also zero emb (for gemm2 atomics)
__global__ __launch_bounds__(256) void prep_kernel(
    const float* __restrict__ src, unsigned short* __restrict__ dst,
    float* __restrict__ emb) {
  const int idx = blockIdx.x * 256 + threadIdx.x;   // 65536 threads, 8 elem each
  float4 a = ((const float4*)src)[idx * 2];
  float4 b = ((const float4*)src)[idx * 2 + 1];
  U16x8 pk;
  pk.us[0] = f2bf(a.x); pk.us[1] = f2bf(a.y); pk.us[2] = f2bf(a.z); pk.us[3] = f2bf(a.w);
  pk.us[4] = f2bf(b.x); pk.us[5] = f2bf(b.y); pk.us[6] = f2bf(b.z); pk.us[7] = f2bf(b.w);
  ((uint4*)dst)[idx] = pk.v;
  if (idx < (B_N * EMB / 4))
    ((float4*)emb)[idx] = make_float4(0.f, 0.f, 0.f, 0.f);
}

// GEMM1: Hp[split][128][4096] fp32 partial of vfs(bf16) @ W_h^T (+b_h split 0).
// grid (128 n-tiles, 4 splits) = 512 blocks (2/CU), 512 thr (16 waves/CU).
// BM=128 (16 rows/wave), BN=32, BK=64, Kchunk=1024, 16 K-steps.
// Pipelined: A direct global->reg (3-slot), W fp32->reg (3-slot) ->cvt->LDS dbuf,
// raw lgkm-only barriers so HBM loads overlap across K-steps.
__global__ __launch_bounds__(512, 4) void gemm1_kernel(
    const unsigned short* __restrict__ Abf, const float* __restrict__ Wh,
    const float* __restrict__ bh, float* __restrict__ Hp) {
  const int n0    = blockIdx.x * 32;
  const int kbase = blockIdx.y * 1024;

  __shared__ __align__(16) unsigned short Ws[2][32 * 64];  // 8 KB, XOR-swizzled

  const int t = threadIdx.x, w = t >> 6, lane = t & 63;
  const int m_lane = lane & 15, kq = lane >> 4;
  f32x4 acc[2] = {};

  // W staging: 32 rows x 64 cols fp32, one float4/thread
  const int wr = t >> 4, Gw = (t & 15) >> 1, sub = (t & 1) * 4;
  const float* Wg = Wh + (size_t)(n0 + wr) * VIS + kbase + (t & 15) * 4;
  const int wofs = wr * 64 + ((Gw ^ (wr & 7)) * 8) + sub;

  // A frags directly from global (L2-resident): row fixed per lane
  const int arow = w * 16 + m_lane;
  const unsigned short* Ag = Abf + (size_t)arow * VIS + kbase + kq * 8;

  float4 wv[3];        // W tiles k, rotating slot = tile % 3
  bf16x8 av[3][2];     // A tiles, [slot][ks]

  wv[0] = *(const float4*)(Wg);
  wv[1] = *(const float4*)(Wg + 64);
  wv[2] = *(const float4*)(Wg + 128);
  av[0][0] = *(const bf16x8*)(Ag);
  av[0][1] = *(const bf16x8*)(Ag + 32);
  av[1][0] = *(const bf16x8*)(Ag + 64);
  av[1][1] = *(const bf16x8*)(Ag + 96);
  {
    U16x4 pk;
    pk.us[0] = f2bf(wv[0].x); pk.us[1] = f2bf(wv[0].y);
    pk.us[2] = f2bf(wv[0].z); pk.us[3] = f2bf(wv[0].w);
    *(uint2*)&Ws[0][wofs] = pk.v;
  }
  PIPE_BARRIER();

#pragma unroll
  for (int k = 0; k < 16; ++k) {
    const int cur = k & 1;
    if (k + 3 < 16) wv[k % 3] = *(const float4*)(Wg + (k + 3) * 64);
    if (k + 2 < 16) {
      av[(k + 2) % 3][0] = *(const bf16x8*)(Ag + (k + 2) * 64);
      av[(k + 2) % 3][1] = *(const bf16x8*)(Ag + (k + 2) * 64 + 32);
    }
    if (k + 1 < 16) {
      const float4 wc = wv[(k + 1) % 3];
      U16x4 pk;
      pk.us[0] = f2bf(wc.x); pk.us[1] = f2bf(wc.y);
      pk.us[2] = f2bf(wc.z); pk.us[3] = f2bf(wc.w);
      *(uint2*)&Ws[1 - cur][wofs] = pk.v;
    }
#pragma unroll
    for (int ks = 0; ks < 2; ++ks) {
      const int Gk = ks * 4 + kq;
      const int cA = m_lane, cB = m_lane + 16;
      bf16x8 b0 = *(const bf16x8*)&Ws[cur][cA * 64 + ((Gk ^ (cA & 7)) * 8)];
      bf16x8 b1 = *(const bf16x8*)&Ws[cur][cB * 64 + ((Gk ^ (cB & 7)) * 8)];
      acc[0] = __builtin_amdgcn_mfma_f32_16x16x32_bf16(av[k % 3][ks], b0, acc[0], 0, 0, 0);
      acc[1] = __builtin_amdgcn_mfma_f32_16x16x32_bf16(av[k % 3][ks], b1, acc[1], 0, 0, 0);
    }
    PIPE_BARRIER();
  }

  // epilogue: C/D layout col=lane&15, row=(lane>>4)*4+r; plain fp32 stores
  float* Pd = Hp + (size_t)blockIdx.y * (B_N * HID);
  const int rq = (lane >> 4) * 4;
#pragma unroll
  for (int ni = 0; ni < 2; ++ni) {
    const int ng = n0 + ni * 16 + m_lane;
    const float bias = (blockIdx.y == 0) ? bh[ng] : 0.0f;
#pragma unroll
    for (int r = 0; r < 4; ++r)
      Pd[(size_t)(w * 16 + rq + r) * HID + ng] = acc[ni][r] + bias;
  }
}

// cvt: Hbf = bf16(sum of 4 Hp planes); fused split-K reduce + downconvert
__global__ __launch_bounds__(256) void cvt_kernel(
    const float* __restrict__ Hp, unsigned short* __restrict__ dst) {
  const int idx = blockIdx.x * 256 + threadIdx.x;   // 65536 threads, 8 elem each
  const size_t PS = (size_t)B_N * HID;
  float4 a = ((const float4*)Hp)[idx * 2];
  float4 b = ((const float4*)Hp)[idx * 2 + 1];
#pragma unroll
  for (int p = 1; p < 4; ++p) {
    float4 ap = ((const float4*)(Hp + p * PS))[idx * 2];
    float4 bp = ((const float4*)(Hp + p * PS))[idx * 2 + 1];
    a.x += ap.x; a.y += ap.y; a.z += ap.z; a.w += ap.w;
    b.x += bp.x; b.y += bp.y; b.z += bp.z; b.w += bp.w;
  }
  U16x8 pk;
  pk.us[0] = f2bf(a.x); pk.us[1] = f2bf(a.y); pk.us[2] = f2bf(a.z); pk.us[3] = f2bf(a.w);
  pk.us[4] = f2bf(b.x); pk.us[5] = f2bf(b.y); pk.us[6] = f2bf(b.z); pk.us[7] = f2bf(b.w);
  ((uint4*)dst)[idx] = pk.v;
}

// GEMM2: emb[128,512] += hidden(bf16) @ W_e^T (+b_e split 0), fp32 atomics.
// grid (32 n-tiles, 8 splits) = 256 blocks, 512 thr. BM=128 (16 rows/wave),
// BN=16, BK=64, Kchunk=512, 8 K-steps. Same raw-barrier pipeline as gemm1.
__global__ __launch_bounds__(512, 4) void gemm2_kernel(
    const unsigned short* __restrict__ Hbf, const float* __restrict__ We,
    const float* __restrict__ be, float* __restrict__ emb) {
  const int n0    = blockIdx.x * 16;
  const int kbase = blockIdx.y * 512;

  __shared__ __align__(16) unsigned short Ws[2][16 * 64];  // 4 KB

  const int t = threadIdx.x, w = t >> 6, lane = t & 63;
  const int m_lane = lane & 15, kq = lane >> 4;
  f32x4 acc = {};

  // W staging: 16 rows x 64 cols fp32, one float2/thread
  const int wr = t >> 5, e = (t & 31) * 2;
  const float* Wg = We + (size_t)(n0 + wr) * HID + kbase + e;
  const int wofs = wr * 64 + (((e >> 3) ^ (wr & 7)) * 8) + (e & 7);

  const int arow = w * 16 + m_lane;
  const unsigned short* Ag = Hbf + (size_t)arow * HID + kbase + kq * 8;

  float2 wv[3];
  bf16x8 av[3][2];

  wv[0] = *(const float2*)(Wg);
  wv[1] = *(const float2*)(Wg + 64);
  wv[2] = *(const float2*)(Wg + 128);
  av[0][0] = *(const bf16x8*)(Ag);
  av[0][1] = *(const bf16x8*)(Ag + 32);
  av[1][0] = *(const bf16x8*)(Ag + 64);
  av[1][1] = *(const bf16x8*)(Ag + 96);
  {
    U16x2 pk;
    pk.us[0] = f2bf(wv[0].x); pk.us[1] = f2bf(wv[0].y);
    *(unsigned*)&Ws[0][wofs] = pk.v;
  }
  PIPE_BARRIER();

#pragma unroll
  for (int k = 0; k < 8; ++k) {
    const int cur = k & 1;
    if (k + 3 < 8) wv[k % 3] = *(const float2*)(Wg + (k + 3) * 64);
    if (k + 2 < 8) {
      av[(k + 2) % 3][0] = *(const bf16x8*)(Ag + (k + 2) * 64);
      av[(k + 2) % 3][1] = *(const bf16x8*)(Ag + (k + 2) * 64 + 32);
    }
    if (k + 1 < 8) {
      const float2 wc = wv[(k + 1) % 3];
      U16x2 pk;
      pk.us[0] = f2bf(wc.x); pk.us[1] = f2bf(wc.y);
      *(unsigned*)&Ws[1 - cur][wofs] = pk.v;
    }
#pragma unroll
    for (int ks = 0; ks < 2; ++ks) {
      const int Gk = ks * 4 + kq;
      bf16x8 b0 = *(const bf16x8*)&Ws[cur][m_lane * 64 + ((Gk ^ (m_lane & 7)) * 8)];
      acc = __builtin_amdgcn_mfma_f32_16x16x32_bf16(av[k % 3][ks], b0, acc, 0, 0, 0);
    }
    PIPE_BARRIER();
  }

  const int rq = (lane >> 4) * 4;
  const int ng = n0 + m_lane;
  const float bias = (blockIdx.y == 0) ? be[ng] : 0.0f;
#pragma unroll
  for (int r = 0; r < 4; ++r)
    atomicAdd(&emb[(w * 16 + rq + r) * EMB + ng], acc[r] + bias);
}

// Scores, e-stationary. Blocks 0..1023: 16 b x 16 negatives. 1024..1031: positives.
__global__ __launch_bounds__(256, 2) void score_kernel(
    const float* __restrict__ emb, const float* __restrict__ n_lfs,
    const float* __restrict__ p_lfs, float* __restrict__ out) {
  const int bx = blockIdx.x;
  const int t = threadIdx.x;
  const int s = t & 15, tb = t >> 4;

  if (bx < 1024) {
    const int nc = bx >> 3, bt = bx & 7;
    const int n0 = nc * 16, b0 = bt * 16;
    __shared__ __align__(16) float nl[16 * 576];
#pragma unroll
    for (int i = 0; i < 8; ++i) {
      const int f = t + i * 256;
      const int r = f >> 7, o4 = f & 127;
      float4 v = *(const float4*)(n_lfs + (size_t)(n0 + r) * EMB + o4 * 4);
      *(float4*)&nl[r * 576 + (o4 >> 3) * 36 + (o4 & 7) * 4] = v;
    }
    const float* eb = emb + (size_t)(b0 + tb) * EMB + s * 32;
    float4 ev[8];
#pragma unroll
    for (int i = 0; i < 8; ++i) ev[i] = *(const float4*)(eb + i * 4);
    __syncthreads();

    for (int j = 0; j < 16; ++j) {
      const float* nr = &nl[j * 576 + s * 36];
      float a0 = 0.f, a1 = 0.f, a2 = 0.f, a3 = 0.f;
#pragma unroll
      for (int i = 0; i < 8; ++i) {
        float4 nv = *(const float4*)(nr + i * 4);
        float d0 = fmaxf(nv.x - ev[i].x, 0.f);
        float d1 = fmaxf(nv.y - ev[i].y, 0.f);
        float d2 = fmaxf(nv.z - ev[i].z, 0.f);
        float d3 = fmaxf(nv.w - ev[i].w, 0.f);
        a0 = fmaf(d0, d0, a0); a1 = fmaf(d1, d1, a1);
        a2 = fmaf(d2, d2, a2); a3 = fmaf(d3, d3, a3);
      }
      float ss = (a0 + a1) + (a2 + a3);
      ss += __shfl_xor(ss, 1);
      ss += __shfl_xor(ss, 2);
      ss += __shfl_xor(ss, 4);
      ss += __shfl_xor(ss, 8);
      if (s == 0) out[(size_t)(b0 + tb) * OUTN + 1 + n0 + j] = -sqrtf(ss);
    }
  } else {
    const int b = (bx - 1024) * 16 + tb;
    const float* eb = emb + (size_t)b * EMB + s * 32;
    const float* pb = p_lfs + (size_t)b * EMB + s * 32;
    float a0 = 0.f, a1 = 0.f, a2 = 0.f, a3 = 0.f;
#pragma unroll
    for (int i = 0; i < 8; ++i) {
      float4 pv = *(const float4*)(pb + i * 4);
      float4 ev = *(const float4*)(eb + i * 4);
      float d0 = fmaxf(pv.x - ev.x, 0.f);
      float d1 = fmaxf(pv.y - ev.y, 0.f);
      float d2 = fmaxf(pv.z - ev.z, 0.f);
      float d3 = fmaxf(pv.w - ev.w, 0.f);
      a0 = fmaf(d0, d0, a0); a1 = fmaf(d1, d1, a1);
      a2 = fmaf(d2, d2, a2); a3 = fmaf(d3, d3, a3);
    }
    float ss = (a0 + a1) + (a2 + a3);
    ss += __shfl_xor(ss, 1);
    ss += __shfl_xor(ss, 2);
    ss += __shfl_xor(ss, 4);
    ss += __shfl_xor(ss, 8);
    if (s == 0) out[(size_t)b * OUTN] = -sqrtf(ss);
  }
}

extern "C" void kernel_launch(void* const* d_in, const int* in_sizes, int n_in,
                              void* d_out, int out_size, void* d_ws, size_t ws_size,
                              hipStream_t stream) {
  const float* vfs   = (const float*)d_in[0];
  const float* p_lfs = (const float*)d_in[1];
  const float* n_lfs = (const float*)d_in[2];
  const float* W_h   = (const float*)d_in[3];
  const float* b_h   = (const float*)d_in[4];
  const float* W_e   = (const float*)d_in[5];
  const float* b_e   = (const float*)d_in[6];
  float* out = (float*)d_out;

  // ws layout (10.25 MB): [Hp 4x2MB][emb 256KB][Abf 1MB][Hbf 1MB]
  char* ws = (char*)d_ws;
  float*          Hp  = (float*)ws;
  float*          emb = (float*)(ws + (8u << 20));
  unsigned short* Abf = (unsigned short*)(ws + (8u << 20) + (256u << 10));
  unsigned short* Hbf = (unsigned short*)(ws + (9u << 20) + (256u << 10));

  prep_kernel<<<256, 256, 0, stream>>>(vfs, Abf, emb);
  gemm1_kernel<<<dim3(HID / 32, 4), 512, 0, stream>>>(Abf, W_h, b_h, Hp);
  cvt_kernel<<<256, 256, 0, stream>>>(Hp, Hbf);
  gemm2_kernel<<<dim3(EMB / 16, 8), 512, 0, stream>>>(Hbf, W_e, b_e, emb);
  score_kernel<<<1032, 256, 0, stream>>>(emb, n_lfs, p_lfs, out);
}